// Round 4
// baseline (1105.955 us; speedup 1.0000x reference)
//
#include <hip/hip_runtime.h>
#include <cfloat>
#include <cmath>

#define NROWS 32768
#define DDIM  512
#define KCODES 2048

// output layout (floats): [loss][q_st N*512][perplexity][encodings N*K]
#define OUT_Q    1
#define OUT_PERP 16777217
#define OUT_ENC  16777218

// scratch offsets in float slots, relative to S = d_out + OUT_ENC + 2
// (capacity 67,108,862 float slots inside the encodings region)
#define H_OFF     0           // 16,777,216  h fp32 [32768][512]
#define AP_OFF    16777216    // 16,777,216  h split bf16 [32768][1024] (hi|lo)
#define BP_OFF    33554432    //  1,048,576  emb split bf16 [2048][1024]
#define XS_OFF    34603008    // 16,777,216  X split bf16 [32768][1024]
#define WS_OFF    51380224    //    262,144  W split bf16 [512][1024]
#define ENORM_OFF 51642368    //      2,048
#define PVAL_OFF  51644416    //  1,048,576 (32 x 32768)
#define PSEC_OFF  52692992    //  1,048,576
#define PIDX_OFF  53741568    //  1,048,576 -> end 54,790,144

#define RESCORE_EPS 0.02f

typedef __attribute__((ext_vector_type(8))) short  bf16x8;
typedef __attribute__((ext_vector_type(4))) float  f32x4;

__device__ __forceinline__ unsigned short f2bf(float f) {
  unsigned u = __float_as_uint(f);
  unsigned r = (u + 0x7FFF + ((u >> 16) & 1)) >> 16;
  return (unsigned short)r;
}
__device__ __forceinline__ float bf2f(unsigned short h) {
  return __uint_as_float(((unsigned)h) << 16);
}
__device__ __forceinline__ void gload16(const void* g, void* l) {
  __builtin_amdgcn_global_load_lds(
      (const __attribute__((address_space(1))) unsigned int*)g,
      (__attribute__((address_space(3))) unsigned int*)l, 16, 0, 0);
}
__device__ __forceinline__ ushort4 hi4(float4 v) {
  return make_ushort4(f2bf(v.x), f2bf(v.y), f2bf(v.z), f2bf(v.w));
}
__device__ __forceinline__ ushort4 lo4(float4 v, ushort4 h) {
  return make_ushort4(f2bf(v.x - bf2f(h.x)), f2bf(v.y - bf2f(h.y)),
                      f2bf(v.z - bf2f(h.z)), f2bf(v.w - bf2f(h.w)));
}

// fp32 [R][256] half -> hi/lo into Xs [R][1024] at column offset colOff
__global__ __launch_bounds__(256) void ksplit_half(const float* __restrict__ src,
    unsigned short* __restrict__ Xs, int colOff) {
  const int tid = blockIdx.x * 256 + threadIdx.x;   // 8192 blocks
  const int n  = tid >> 6;
  const int c4 = (tid & 63) * 4;
  const float4 v = *(const float4*)&src[(size_t)n * 256 + c4];
  const ushort4 h = hi4(v);
  unsigned short* row = Xs + (size_t)n * 1024;
  *(ushort4*)&row[colOff + c4]       = h;
  *(ushort4*)&row[512 + colOff + c4] = lo4(v, h);
}

// fp32 [R][512] -> hi/lo into dst [R][1024]
__global__ __launch_bounds__(256) void ksplit_full(const float* __restrict__ src,
    unsigned short* __restrict__ dst) {
  const int tid = blockIdx.x * 256 + threadIdx.x;
  const int r  = tid >> 7;
  const int c4 = (tid & 127) * 4;
  const float4 v = *(const float4*)&src[(size_t)r * 512 + c4];
  const ushort4 h = hi4(v);
  unsigned short* row = dst + (size_t)r * 1024;
  *(ushort4*)&row[c4]       = h;
  *(ushort4*)&row[512 + c4] = lo4(v, h);
}

__global__ __launch_bounds__(64) void kenorm(const float* __restrict__ emb,
                                             float* __restrict__ enorms) {
  const int k = blockIdx.x;
  const int t = threadIdx.x;
  float s = 0.f;
#pragma unroll
  for (int i = 0; i < 8; ++i) {
    const float v = emb[k * DDIM + t + i * 64];
    s = fmaf(v, v, s);
  }
#pragma unroll
  for (int off = 32; off > 0; off >>= 1) s += __shfl_down(s, off);
  if (t == 0) enorms[k] = s;
}

// h = X @ W^T + b via split-bf16 MFMA (3-term: hi*hi, lo*hi, hi*lo).
// Writes h fp32 [32768][512] and Ap = split(h) bf16 [32768][1024].
__global__ __launch_bounds__(256) void kgemm1_mfma(
    const unsigned short* __restrict__ Xs, const unsigned short* __restrict__ Ws,
    const float* __restrict__ bias, float* __restrict__ h,
    unsigned short* __restrict__ Ap) {
  __shared__ short Asm[128 * 64];
  __shared__ short Bsm[128 * 64];
  const int bid = blockIdx.x;               // 1024 blocks
  const int n = (bid >> 3) & 3;
  const int m = (bid & 7) * 32 + (bid >> 5);
  const int m0 = m * 128, j0 = n * 128;
  const int t = threadIdx.x;
  const int wid = t >> 6, wr = wid >> 1, wc = wid & 1;
  const int lr = t & 15, lg = (t >> 4) & 3;

  f32x4 acc[4][4];
#pragma unroll
  for (int mi = 0; mi < 4; ++mi)
#pragma unroll
    for (int ni = 0; ni < 4; ++ni) acc[mi][ni] = (f32x4){0.f, 0.f, 0.f, 0.f};

  for (int kt = 0; kt < 24; ++kt) {
    const int ph = kt >> 3, r64 = (kt & 7) * 64;
    const int koffA = (ph == 1) ? 512 + r64 : r64;  // hi, lo, hi
    const int koffB = (ph == 2) ? 512 + r64 : r64;  // hi, hi, lo
    const unsigned short* Ag = Xs + (size_t)m0 * 1024 + koffA;
    const unsigned short* Bg = Ws + (size_t)j0 * 1024 + koffB;
#pragma unroll
    for (int i = 0; i < 4; ++i) {
      const int chunk = i * 256 + t;
      const int r = chunk >> 3;
      const int c8s = (chunk & 7) ^ (r & 7);        // source-permute swizzle
      gload16(Ag + (size_t)r * 1024 + c8s * 8, &Asm[chunk * 8]);
      gload16(Bg + (size_t)r * 1024 + c8s * 8, &Bsm[chunk * 8]);
    }
    __syncthreads();
#pragma unroll
    for (int kk = 0; kk < 2; ++kk) {
      const int xk = (kk * 32 + lg * 8) ^ ((lr & 7) << 3);   // XOR'd read
      bf16x8 a[4], b[4];
#pragma unroll
      for (int mi = 0; mi < 4; ++mi)
        a[mi] = *(const bf16x8*)&Asm[(wr * 64 + mi * 16 + lr) * 64 + xk];
#pragma unroll
      for (int ni = 0; ni < 4; ++ni)
        b[ni] = *(const bf16x8*)&Bsm[(wc * 64 + ni * 16 + lr) * 64 + xk];
#pragma unroll
      for (int mi = 0; mi < 4; ++mi)
#pragma unroll
        for (int ni = 0; ni < 4; ++ni)
          acc[mi][ni] = __builtin_amdgcn_mfma_f32_16x16x32_bf16(a[mi], b[ni], acc[mi][ni], 0, 0, 0);
    }
    __syncthreads();
  }
#pragma unroll
  for (int ni = 0; ni < 4; ++ni) {
    const int col = j0 + wc * 64 + ni * 16 + lr;
    const float bb = bias[col];
#pragma unroll
    for (int mi = 0; mi < 4; ++mi)
#pragma unroll
      for (int jj = 0; jj < 4; ++jj) {
        const int row = m0 + wr * 64 + mi * 16 + lg * 4 + jj;
        const float v = acc[mi][ni][jj] + bb;
        h[(size_t)row * 512 + col] = v;
        const unsigned short hb = f2bf(v);
        Ap[(size_t)row * 1024 + col]       = hb;
        Ap[(size_t)row * 1024 + 512 + col] = f2bf(v - bf2f(hb));
      }
  }
}

// MFMA split-bf16 distance GEMM + per-row best/second argmin partials.
// grid 4096 (256 m x 16 n, XCD-swizzled), 4 waves 2x2; partial p = n*2+wc.
__global__ __launch_bounds__(256) void kdist_mfma(
    const unsigned short* __restrict__ Ap, const unsigned short* __restrict__ Bp,
    const float* __restrict__ enorms, float* __restrict__ pval,
    float* __restrict__ psec, int* __restrict__ pidx) {
  __shared__ short Asm[128 * 64];
  __shared__ short Bsm[128 * 64];
  const int bid = blockIdx.x;
  const int m = (bid & 7) * 32 + (bid >> 7);
  const int n = (bid >> 3) & 15;
  const int m0 = m * 128;
  const int n0 = n * 128;
  const int t = threadIdx.x;
  const int wid = t >> 6, wr = wid >> 1, wc = wid & 1;
  const int lr = t & 15, lg = (t >> 4) & 3;

  f32x4 acc[4][4];
#pragma unroll
  for (int mi = 0; mi < 4; ++mi)
#pragma unroll
    for (int ni = 0; ni < 4; ++ni) acc[mi][ni] = (f32x4){0.f, 0.f, 0.f, 0.f};

  for (int kt = 0; kt < 24; ++kt) {
    const int ph = kt >> 3, r64 = (kt & 7) * 64;
    const int koffA = (ph == 1) ? 512 + r64 : r64;  // h: hi, lo, hi
    const int koffB = (ph == 2) ? 512 + r64 : r64;  // e: hi, hi, lo
    const unsigned short* Ag = Ap + (size_t)m0 * 1024 + koffA;
    const unsigned short* Bg = Bp + (size_t)n0 * 1024 + koffB;
#pragma unroll
    for (int i = 0; i < 4; ++i) {
      const int chunk = i * 256 + t;
      const int r = chunk >> 3;
      const int c8s = (chunk & 7) ^ (r & 7);
      gload16(Ag + (size_t)r * 1024 + c8s * 8, &Asm[chunk * 8]);
      gload16(Bg + (size_t)r * 1024 + c8s * 8, &Bsm[chunk * 8]);
    }
    __syncthreads();
#pragma unroll
    for (int kk = 0; kk < 2; ++kk) {
      const int xk = (kk * 32 + lg * 8) ^ ((lr & 7) << 3);
      bf16x8 a[4], b[4];
#pragma unroll
      for (int mi = 0; mi < 4; ++mi)
        a[mi] = *(const bf16x8*)&Asm[(wr * 64 + mi * 16 + lr) * 64 + xk];
#pragma unroll
      for (int ni = 0; ni < 4; ++ni)
        b[ni] = *(const bf16x8*)&Bsm[(wc * 64 + ni * 16 + lr) * 64 + xk];
#pragma unroll
      for (int mi = 0; mi < 4; ++mi)
#pragma unroll
        for (int ni = 0; ni < 4; ++ni)
          acc[mi][ni] = __builtin_amdgcn_mfma_f32_16x16x32_bf16(a[mi], b[ni], acc[mi][ni], 0, 0, 0);
    }
    __syncthreads();
  }

  float en[4]; int kb[4];
#pragma unroll
  for (int ni = 0; ni < 4; ++ni) {
    kb[ni] = n0 + wc * 64 + ni * 16 + lr;
    en[ni] = enorms[kb[ni]];
  }
  const int p = n * 2 + wc;
#pragma unroll
  for (int mi = 0; mi < 4; ++mi)
#pragma unroll
    for (int j = 0; j < 4; ++j) {
      float bv = fmaf(-2.f, acc[mi][0][j], en[0]);
      int bk = kb[0];
      float sv = FLT_MAX;
#pragma unroll
      for (int ni = 1; ni < 4; ++ni) {
        const float v = fmaf(-2.f, acc[mi][ni][j], en[ni]);
        if (v < bv) { sv = bv; bv = v; bk = kb[ni]; }
        else sv = fminf(sv, v);
      }
#pragma unroll
      for (int msk = 1; msk < 16; msk <<= 1) {
        const float ob = __shfl_xor(bv, msk);
        const int   ok = __shfl_xor(bk, msk);
        const float os = __shfl_xor(sv, msk);
        if (ob < bv || (ob == bv && ok < bk)) { sv = fminf(bv, os); bv = ob; bk = ok; }
        else sv = fminf(sv, ob);
      }
      if (lr == 0) {
        const int row = m0 + wr * 64 + mi * 16 + lg * 4 + j;
        pval[p * NROWS + row] = bv;
        psec[p * NROWS + row] = sv;
        pidx[p * NROWS + row] = bk;
      }
    }
}

// merge 32 panel partials -> global best; flag ambiguous rows
__global__ __launch_bounds__(256) void kreduce(const float* __restrict__ pval,
    const float* __restrict__ psec, const int* __restrict__ pidx,
    int* __restrict__ idx, int* __restrict__ nflag, int* __restrict__ flags) {
  const int r = blockIdx.x * 256 + threadIdx.x;
  float bv = FLT_MAX, sv = FLT_MAX;
  int bk = 0;
#pragma unroll
  for (int p = 0; p < 32; ++p) {
    const float v1 = pval[p * NROWS + r];
    const int   k1 = pidx[p * NROWS + r];
    const float s1 = psec[p * NROWS + r];
    if (v1 < bv || (v1 == bv && k1 < bk)) { sv = fminf(bv, s1); bv = v1; bk = k1; }
    else sv = fminf(sv, v1);
  }
  idx[r] = bk;
  if (sv - bv < RESCORE_EPS) {
    const int pos = atomicAdd(nflag, 1);
    flags[pos] = r;
  }
}

// exact rescore for flagged rows, batched 8 rows/block:
// recompute h exactly (fp32) from X,W then full fp32 distance sweep.
__global__ __launch_bounds__(256) void krescore(const float* __restrict__ x0,
    const float* __restrict__ x1, const float* __restrict__ W,
    const float* __restrict__ bias, const float* __restrict__ emb,
    const float* __restrict__ enorms, const int* __restrict__ flags,
    const int* __restrict__ nflag, int* __restrict__ idx) {
  __shared__ float Xr[8 * 512];
  __shared__ float hr[8 * 512];
  __shared__ float rv[256];
  __shared__ int   rk[256];
  const int t = threadIdx.x;
  const int nf = *nflag;
  for (int g = blockIdx.x; g * 8 < nf; g += gridDim.x) {
    __syncthreads();
    // stage 8 X rows (pad with row flags[nf-1])
    for (int i = t; i < 8 * 128; i += 256) {
      const int rr = i >> 7;
      const int c4 = (i & 127) * 4;
      const int fi = g * 8 + rr;
      const int r = flags[fi < nf ? fi : nf - 1];
      const float* src = (c4 < 256) ? (x0 + (size_t)r * 256 + c4)
                                    : (x1 + (size_t)r * 256 + (c4 - 256));
      *(float4*)&Xr[rr * 512 + c4] = *(const float4*)src;
    }
    __syncthreads();
    // exact h for the 8 rows: thread t computes cols t and t+256
#pragma unroll
    for (int jj = 0; jj < 2; ++jj) {
      const int j = t + jj * 256;
      float s[8];
#pragma unroll
      for (int rr = 0; rr < 8; ++rr) s[rr] = bias[j];
      for (int d = 0; d < 512; d += 4) {
        const float4 w4 = *(const float4*)&W[(size_t)j * 512 + d];
#pragma unroll
        for (int rr = 0; rr < 8; ++rr) {
          const float4 xv = *(const float4*)&Xr[rr * 512 + d];
          s[rr] = fmaf(xv.x, w4.x, s[rr]);
          s[rr] = fmaf(xv.y, w4.y, s[rr]);
          s[rr] = fmaf(xv.z, w4.z, s[rr]);
          s[rr] = fmaf(xv.w, w4.w, s[rr]);
        }
      }
#pragma unroll
      for (int rr = 0; rr < 8; ++rr) hr[rr * 512 + j] = s[rr];
    }
    __syncthreads();
    // distance sweep: thread handles codes k = t..2047 step 256
    float bv[8]; int bk[8];
#pragma unroll
    for (int rr = 0; rr < 8; ++rr) { bv[rr] = FLT_MAX; bk[rr] = 0; }
    for (int k = t; k < KCODES; k += 256) {
      float dot[8];
#pragma unroll
      for (int rr = 0; rr < 8; ++rr) dot[rr] = 0.f;
      for (int d = 0; d < 512; d += 4) {
        const float4 e4 = *(const float4*)&emb[(size_t)k * 512 + d];
#pragma unroll
        for (int rr = 0; rr < 8; ++rr) {
          const float4 hv = *(const float4*)&hr[rr * 512 + d];
          dot[rr] = fmaf(hv.x, e4.x, dot[rr]);
          dot[rr] = fmaf(hv.y, e4.y, dot[rr]);
          dot[rr] = fmaf(hv.z, e4.z, dot[rr]);
          dot[rr] = fmaf(hv.w, e4.w, dot[rr]);
        }
      }
      const float en = enorms[k];
#pragma unroll
      for (int rr = 0; rr < 8; ++rr) {
        const float v = fmaf(-2.f, dot[rr], en);
        if (v < bv[rr]) { bv[rr] = v; bk[rr] = k; }
      }
    }
    // per-row block argmin
#pragma unroll
    for (int rr = 0; rr < 8; ++rr) {
      __syncthreads();
      rv[t] = bv[rr]; rk[t] = bk[rr];
      __syncthreads();
      for (int off = 128; off > 0; off >>= 1) {
        if (t < off) {
          const float v2 = rv[t + off];
          const int   k2 = rk[t + off];
          if (v2 < rv[t] || (v2 == rv[t] && k2 < rk[t])) { rv[t] = v2; rk[t] = k2; }
        }
        __syncthreads();
      }
      if (t == 0 && g * 8 + rr < nf) idx[flags[g * 8 + rr]] = rk[0];
    }
  }
}

__global__ __launch_bounds__(256) void kquant(const float* __restrict__ h,
    const float* __restrict__ emb, const int* __restrict__ idx,
    float* __restrict__ qout, double* __restrict__ loss_accum) {
  const int tid = blockIdx.x * 256 + threadIdx.x;
  float ls = 0.f;
#pragma unroll
  for (int i = 0; i < 4; ++i) {
    const int f = tid + i * 4194304;
    const int n = f >> 9;
    const int c = f & 511;
    const float hv = h[f];
    const float ev = emb[(size_t)idx[n] * DDIM + c];
    qout[f] = hv + (ev - hv);
    const float d = ev - hv;
    ls = fmaf(d, d, ls);
  }
  double s = (double)ls;
#pragma unroll
  for (int off = 32; off > 0; off >>= 1) s += __shfl_down(s, off);
  __shared__ double sred[4];
  if ((threadIdx.x & 63) == 0) sred[threadIdx.x >> 6] = s;
  __syncthreads();
  if (threadIdx.x == 0)
    atomicAdd(loss_accum, sred[0] + sred[1] + sred[2] + sred[3]);
}

__global__ __launch_bounds__(256) void khist(const int* __restrict__ idx,
                                             int* __restrict__ counts) {
  const int n = blockIdx.x * 256 + threadIdx.x;
  atomicAdd(&counts[idx[n]], 1);
}

__global__ __launch_bounds__(256) void kenc(const int* __restrict__ idx,
                                            float2* __restrict__ out2) {
  const int nt = 2048 * 256;
  for (int f2 = blockIdx.x * 256 + threadIdx.x; f2 < 33554432; f2 += nt) {
    const int n  = f2 >> 10;
    const int k  = (f2 & 1023) << 1;
    const int in = idx[n];
    out2[f2] = make_float2(in == k ? 1.f : 0.f, in == (k + 1) ? 1.f : 0.f);
  }
}

__global__ __launch_bounds__(256) void kfinal(const double* __restrict__ loss_accum,
    const int* __restrict__ counts, float* __restrict__ out) {
  __shared__ double sred[256];
  const int t = threadIdx.x;
  double s = 0.0;
  for (int k = t; k < KCODES; k += 256) {
    const double p = counts[k] / 32768.0;
    s += p * log(p + 1e-10);
  }
  sred[t] = s;
  __syncthreads();
  for (int off = 128; off > 0; off >>= 1) {
    if (t < off) sred[t] += sred[t + off];
    __syncthreads();
  }
  if (t == 0) {
    out[0]        = (float)(0.25 * loss_accum[0] / (32768.0 * 512.0));
    out[OUT_PERP] = (float)exp(-sred[0]);
  }
}

extern "C" void kernel_launch(void* const* d_in, const int* in_sizes, int n_in,
                              void* d_out, int out_size, void* d_ws, size_t ws_size,
                              hipStream_t stream) {
  const float* x0  = (const float*)d_in[0];
  const float* x1  = (const float*)d_in[1];
  const float* W   = (const float*)d_in[2];
  const float* b   = (const float*)d_in[3];
  const float* emb = (const float*)d_in[4];
  float* out = (float*)d_out;
  float* S   = out + OUT_ENC + 2;

  unsigned short* Ap = (unsigned short*)(S + AP_OFF);
  unsigned short* Bp = (unsigned short*)(S + BP_OFF);
  unsigned short* Xs = (unsigned short*)(S + XS_OFF);
  unsigned short* Ws = (unsigned short*)(S + WS_OFF);
  int* pidx = (int*)(S + PIDX_OFF);

  double* loss_accum = (double*)d_ws;
  int* nflag  = (int*)((char*)d_ws + 8);
  int* counts = (int*)((char*)d_ws + 16);
  int* idx    = (int*)((char*)d_ws + 8208);
  int* flags  = (int*)((char*)d_ws + 139280);

  hipMemsetAsync(d_ws, 0, 8208, stream);

  ksplit_half<<<8192, 256, 0, stream>>>(x0, Xs, 0);
  ksplit_half<<<8192, 256, 0, stream>>>(x1, Xs, 256);
  ksplit_full<<<256,  256, 0, stream>>>(W, Ws);
  ksplit_full<<<1024, 256, 0, stream>>>(emb, Bp);
  kenorm<<<2048, 64, 0, stream>>>(emb, S + ENORM_OFF);
  kgemm1_mfma<<<1024, 256, 0, stream>>>(Xs, Ws, b, S + H_OFF, Ap);
  kdist_mfma<<<4096, 256, 0, stream>>>(Ap, Bp, S + ENORM_OFF,
                                       S + PVAL_OFF, S + PSEC_OFF, pidx);
  kreduce<<<128, 256, 0, stream>>>(S + PVAL_OFF, S + PSEC_OFF, pidx, idx, nflag, flags);
  krescore<<<128, 256, 0, stream>>>(x0, x1, W, b, emb, S + ENORM_OFF,
                                    flags, nflag, idx);
  kquant<<<16384, 256, 0, stream>>>(S + H_OFF, emb, idx, out + OUT_Q, loss_accum);
  khist<<<128, 256, 0, stream>>>(idx, counts);
  kenc<<<2048, 256, 0, stream>>>(idx, (float2*)(out + OUT_ENC));
  kfinal<<<1, 256, 0, stream>>>(loss_accum, counts, out);
}